// Round 26
// baseline (58.162 us; speedup 1.0000x reference)
//
#include <hip/hip_runtime.h>

#define NNODES 4194304
#define NGRAPH 16384

typedef _Float16 half4 __attribute__((ext_vector_type(4)));
typedef float floatx4 __attribute__((ext_vector_type(4)));
typedef unsigned int uint;

__device__ __forceinline__ uint pk_u32(float lo, float hi) {
  return __builtin_bit_cast(uint, __builtin_amdgcn_cvt_pkrtz(lo, hi));
}

__device__ __forceinline__ half4 relu_cvt(floatx4 d) {
  uint2 u;
  u.x = pk_u32(d[0], d[1]);
  u.y = pk_u32(d[2], d[3]);
  half4 h = __builtin_bit_cast(half4, u);
  return __builtin_elementwise_max(h, half4{0, 0, 0, 0});
}

// DPP butterfly wave64 sum; total lands in lane 63.
template <int CTRL>
__device__ __forceinline__ float dpp_add(float x) {
  int y = __builtin_amdgcn_update_dpp(0, __builtin_bit_cast(int, x), CTRL,
                                      0xf, 0xf, true);
  return x + __builtin_bit_cast(float, y);
}
__device__ __forceinline__ float wave_sum(float x) {
  x = dpp_add<0x111>(x);
  x = dpp_add<0x112>(x);
  x = dpp_add<0x114>(x);
  x = dpp_add<0x118>(x);
  x = dpp_add<0x142>(x);
  x = dpp_add<0x143>(x);
  return x;
}

// Graph boundary scan: start[g] for g in [0, NGRAPH], each written exactly
// once (batch sorted). Empty graphs get start == start of next non-empty.
__global__ __launch_bounds__(256) void scan_kernel(
    const int* __restrict__ batch, int* __restrict__ start) {
  int i = blockIdx.x * 256 + threadIdx.x;
  int b0 = batch[i];
  if (i == 0) {
    for (int g = 0; g <= b0; ++g) start[g] = 0;
  }
  if (i == NNODES - 1) {
    for (int g = b0 + 1; g <= NGRAPH; ++g) start[g] = NNODES;
  } else {
    int b1 = batch[i + 1];
    for (int g = b0 + 1; g <= b1; ++g) start[g] = i + 1;
  }
}

// Prepack: 13 A-fragment tiles of mfma_f32_16x16x16f16 (W as A: M=out,K=in).
//   tiles 0-3:  W1 variant g: weights ONLY at k=4g..4g+3 (group g's B rows
//               read from koct=g lanes = each node's own lane). kk=k-4g:
//               kk<3: W1[row*3+kk]; kk==3: B1[row] / row10=1.0 (bias-1)
//   tile 4: L2a (W2 rows0-15; k10=B2)     tile 5: L2b (rows16-19; k10; row4=1)
//   tile 6: L3a (W3 k0-15)                tile 7: L3b (k16-19; k4=B3; row10=1)
//   tile 8: L4 (W4; k10=B4; row5=1)
//   tiles 9-12: W5 variant g: output row at M=4g (w lands in koct=g lanes'
//               reg0 = own node). row==4g: k<5=W5[k]; k5=B5.
__global__ void prepack_kernel(
    const float* __restrict__ W1, const float* __restrict__ W2,
    const float* __restrict__ W3, const float* __restrict__ W4,
    const float* __restrict__ W5, const float* __restrict__ B1,
    const float* __restrict__ B2, const float* __restrict__ B3,
    const float* __restrict__ B4, const float* __restrict__ B5,
    uint2* __restrict__ Wf) {
  int p = blockIdx.x * 256 + threadIdx.x;
  if (p >= 832) return;
  int tile = p >> 6, lane = p & 63, row = lane & 15, kb = (lane >> 4) * 4;
  float v[4];
#pragma unroll
  for (int i = 0; i < 4; ++i) {
    int k = kb + i;
    float x = 0.f;
    if (tile < 4) {            // W1 variant g = tile
      int kk = k - 4 * tile;
      if (kk >= 0 && kk < 4) {
        if (kk < 3) { if (row < 10) x = W1[row * 3 + kk]; }
        else { if (row < 10) x = B1[row]; else if (row == 10) x = 1.f; }
      }
    } else if (tile == 4) {    // L2a
      if (k < 10) x = W2[row * 10 + k];
      else if (k == 10) x = B2[row];
    } else if (tile == 5) {    // L2b
      if (row < 4 && k < 10) x = W2[(16 + row) * 10 + k];
      if (k == 10) { if (row < 4) x = B2[16 + row]; else if (row == 4) x = 1.f; }
    } else if (tile == 6) {    // L3a
      if (row < 10 && k < 16) x = W3[row * 20 + k];
    } else if (tile == 7) {    // L3b
      if (row < 10 && k < 4) x = W3[row * 20 + 16 + k];
      if (k == 4) { if (row < 10) x = B3[row]; else if (row == 10) x = 1.f; }
    } else if (tile == 8) {    // L4
      if (row < 5 && k < 10) x = W4[row * 10 + k];
      if (k == 10) { if (row < 5) x = B4[row]; else if (row == 5) x = 1.f; }
    } else {                   // W5 variant g = tile-9, output at M row 4g
      int g = tile - 9;
      if (row == 4 * g) {
        if (k < 5) x = W5[k];
        else if (k == 5) x = B5[0];
      }
    }
    v[i] = x;
  }
  Wf[p] = uint2{pk_u32(v[0], v[1]), pk_u32(v[2], v[3])};
}

__device__ __forceinline__ floatx4 mfma16(half4 a, half4 b, floatx4 c) {
  return __builtin_amdgcn_mfma_f32_16x16x16f16(a, b, c, 0, 0, 0);
}

// One WAVE per graph; ZERO cross-lane ops in the MLP (weight-variant scheme:
// every lane's B operand and output are its OWN node's data).
__global__ __launch_bounds__(1024, 8) void fused_kernel(
    const float* __restrict__ t, const float2* __restrict__ pos,
    const float* __restrict__ poi_t, const float2* __restrict__ poi_pos,
    const int* __restrict__ start, const uint2* __restrict__ Wf,
    float* __restrict__ out) {
  const int tid = threadIdx.x;
  const int lane = tid & 63;
  const int wid = tid >> 6;
  const int koct = lane >> 4;
  const int g = blockIdx.x * 16 + wid;

  int s = start[g], e = start[g + 1];
  float2 pp = poi_pos[g];
  float pt = poi_t[g];
  int niter = (e - s + 63) >> 6;

  // ---- Centroid (depth-1 pipelined load->reduce) ----
  float cx = 0.f, cy = 0.f;
  {
    int idx0 = s + lane;
    float2 pA = pos[min(idx0, NNODES - 1)];
    for (int it = 0; it < niter; ++it) {
      int nidx = s + (it + 1) * 64 + lane;
      float2 pB;
      if (it + 1 < niter) pB = pos[min(nidx, NNODES - 1)];
      int idx = s + it * 64 + lane;
      if (idx < e) { cx += pA.x; cy += pA.y; }
      pA = pB;
    }
  }
  cx = wave_sum(cx);
  cy = wave_sum(cy);
  cx = __shfl(cx, 63);
  cy = __shfl(cy, 63);
  float dcx = cx - pp.x, dcy = cy - pp.y;
  float invc = rsqrtf(dcx * dcx + dcy * dcy);
  float ucx = dcx * invc, ucy = dcy * invc;

  // Weight A-fragments: 4x W1-variant, 5 shared mids, 4x W5-variant.
  half4 wa1[4], wl[5], wa5[4];
#pragma unroll
  for (int k = 0; k < 4; ++k)
    wa1[k] = __builtin_bit_cast(half4, Wf[k * 64 + lane]);
#pragma unroll
  for (int k = 0; k < 5; ++k)
    wl[k] = __builtin_bit_cast(half4, Wf[(4 + k) * 64 + lane]);
#pragma unroll
  for (int k = 0; k < 4; ++k)
    wa5[k] = __builtin_bit_cast(half4, Wf[(9 + k) * 64 + lane]);
  floatx4 cz{0.f, 0.f, 0.f, 0.f};

  // ---- MLP + weighted-unit accumulation (depth-1 pipelined, no shuffles) ----
  float ox = 0.f, oy = 0.f;
  {
    int idx0c = min(s + lane, NNODES - 1);
    float tvA = t[idx0c];
    float2 pvA = pos[idx0c];
    for (int it = 0; it < niter; ++it) {
      float tvB;
      float2 pvB;
      if (it + 1 < niter) {
        int nidxc = min(s + (it + 1) * 64 + lane, NNODES - 1);
        tvB = t[nidxc];
        pvB = pos[nidxc];
      }

      int idx = s + it * 64 + lane;
      bool valid = idx < e;
      float f0 = tvA - pt;
      float dpx = pvA.x - pp.x, dpy = pvA.y - pp.y;
      float f1 = dpx * dpx + dpy * dpy;
      float invr = rsqrtf(f1);
      float f2 = (dpx * ucx + dpy * ucy) * invr;
      // Own features as B operand; W1 variant g reads group g's k-rows from
      // koct=g lanes, so no cross-lane gather is needed.
      half4 b1 = __builtin_bit_cast(half4,
                                    uint2{pk_u32(f0, f1), pk_u32(f2, 1.0f)});

      floatx4 d[4];
      half4 a[4];
#pragma unroll
      for (int c = 0; c < 4; ++c) d[c] = mfma16(wa1[c], b1, cz);     // L1
#pragma unroll
      for (int c = 0; c < 4; ++c) a[c] = relu_cvt(d[c]);

      floatx4 d2[4];
      half4 a3a[4], a3b[4];
#pragma unroll
      for (int c = 0; c < 4; ++c) d2[c] = mfma16(wl[0], a[c], cz);   // L2a
#pragma unroll
      for (int c = 0; c < 4; ++c) a3a[c] = relu_cvt(d2[c]);
#pragma unroll
      for (int c = 0; c < 4; ++c) d2[c] = mfma16(wl[1], a[c], cz);   // L2b
#pragma unroll
      for (int c = 0; c < 4; ++c) a3b[c] = relu_cvt(d2[c]);

#pragma unroll
      for (int c = 0; c < 4; ++c) d[c] = mfma16(wl[2], a3a[c], cz);  // L3a
#pragma unroll
      for (int c = 0; c < 4; ++c) d[c] = mfma16(wl[3], a3b[c], d[c]); // L3b
#pragma unroll
      for (int c = 0; c < 4; ++c) a[c] = relu_cvt(d[c]);

#pragma unroll
      for (int c = 0; c < 4; ++c) d[c] = mfma16(wl[4], a[c], cz);    // L4
#pragma unroll
      for (int c = 0; c < 4; ++c) a[c] = relu_cvt(d[c]);

#pragma unroll
      for (int c = 0; c < 4; ++c) d[c] = mfma16(wa5[c], a[c], cz);   // L5

      // w for own node: variant g==koct put it in d[koct][0] (static select).
      float w = d[0][0];
      w = (koct == 1) ? d[1][0] : w;
      w = (koct == 2) ? d[2][0] : w;
      w = (koct == 3) ? d[3][0] : w;
      float invn = (f1 > 0.f) ? invr : 0.f;
      if (valid) {
        ox += w * dpx * invn;
        oy += w * dpy * invn;
      }

      tvA = tvB;
      pvA = pvB;
    }
  }

  ox = wave_sum(ox);
  oy = wave_sum(oy);
  if (lane == 63) ((float2*)out)[g] = float2{ox, oy};
}

extern "C" void kernel_launch(void* const* d_in, const int* in_sizes, int n_in,
                              void* d_out, int out_size, void* d_ws,
                              size_t ws_size, hipStream_t stream) {
  const float* t = (const float*)d_in[0];
  const float2* pos = (const float2*)d_in[1];
  const float* poi_t = (const float*)d_in[2];
  const float2* poi_pos = (const float2*)d_in[3];
  const int* batch = (const int*)d_in[4];
  const float* W1 = (const float*)d_in[5];
  const float* B1 = (const float*)d_in[6];
  const float* W2 = (const float*)d_in[7];
  const float* B2 = (const float*)d_in[8];
  const float* W3 = (const float*)d_in[9];
  const float* B3 = (const float*)d_in[10];
  const float* W4 = (const float*)d_in[11];
  const float* B4 = (const float*)d_in[12];
  const float* W5 = (const float*)d_in[13];
  const float* B5 = (const float*)d_in[14];
  float* out = (float*)d_out;

  int* start = (int*)d_ws;                     // [NGRAPH+1]
  uint2* Wf = (uint2*)(start + NGRAPH + 1);    // [832]

  prepack_kernel<<<4, 256, 0, stream>>>(W1, W2, W3, W4, W5, B1, B2, B3, B4,
                                        B5, Wf);
  scan_kernel<<<NNODES / 256, 256, 0, stream>>>(batch, start);
  fused_kernel<<<NGRAPH / 16, 1024, 0, stream>>>(t, pos, poi_t, poi_pos,
                                                 start, Wf, out);
}

// Round 27
// 46.213 us; speedup vs baseline: 1.2586x; 1.2586x over previous
//
#include <hip/hip_runtime.h>

#define NNODES 4194304
#define NGRAPH 16384

typedef _Float16 half4 __attribute__((ext_vector_type(4)));
typedef float floatx4 __attribute__((ext_vector_type(4)));
typedef unsigned int uint;

__device__ __forceinline__ uint pk_u32(float lo, float hi) {
  return __builtin_bit_cast(uint, __builtin_amdgcn_cvt_pkrtz(lo, hi));
}

__device__ __forceinline__ half4 relu_cvt(floatx4 d) {
  uint2 u;
  u.x = pk_u32(d[0], d[1]);
  u.y = pk_u32(d[2], d[3]);
  half4 h = __builtin_bit_cast(half4, u);
  return __builtin_elementwise_max(h, half4{0, 0, 0, 0});
}

// DPP butterfly wave64 sum; total lands in lane 63.
template <int CTRL>
__device__ __forceinline__ float dpp_add(float x) {
  int y = __builtin_amdgcn_update_dpp(0, __builtin_bit_cast(int, x), CTRL,
                                      0xf, 0xf, true);
  return x + __builtin_bit_cast(float, y);
}
__device__ __forceinline__ float wave_sum(float x) {
  x = dpp_add<0x111>(x);
  x = dpp_add<0x112>(x);
  x = dpp_add<0x114>(x);
  x = dpp_add<0x118>(x);
  x = dpp_add<0x142>(x);
  x = dpp_add<0x143>(x);
  return x;
}

// Graph boundary scan: start[g] for g in [0, NGRAPH], each written exactly
// once (batch sorted). Empty graphs get start == start of next non-empty.
__global__ __launch_bounds__(256) void scan_kernel(
    const int* __restrict__ batch, int* __restrict__ start) {
  int i = blockIdx.x * 256 + threadIdx.x;
  int b0 = batch[i];
  if (i == 0) {
    for (int g = 0; g <= b0; ++g) start[g] = 0;
  }
  if (i == NNODES - 1) {
    for (int g = b0 + 1; g <= NGRAPH; ++g) start[g] = NNODES;
  } else {
    int b1 = batch[i + 1];
    for (int g = b0 + 1; g <= b1; ++g) start[g] = i + 1;
  }
}

// Prepack weights into A-fragments of mfma_f32_16x16x16f16 (W as A: M=out,K=in).
// ALL biases folded via fake constant-1 neurons. 7 tiles, 448 uint2.
__global__ void prepack_kernel(
    const float* __restrict__ W1, const float* __restrict__ W2,
    const float* __restrict__ W3, const float* __restrict__ W4,
    const float* __restrict__ W5, const float* __restrict__ B1,
    const float* __restrict__ B2, const float* __restrict__ B3,
    const float* __restrict__ B4, const float* __restrict__ B5,
    uint2* __restrict__ Wf) {
  int p = blockIdx.x * 256 + threadIdx.x;
  if (p >= 448) return;
  int tile = p >> 6, lane = p & 63, row = lane & 15, kb = (lane >> 4) * 4;
  float v[4];
#pragma unroll
  for (int i = 0; i < 4; ++i) {
    int k = kb + i;
    float x = 0.f;
    switch (tile) {
      case 0:  // W1 (10x3); k=3: B1; row10 = bias-1 neuron
        if (row < 10 && k < 3) x = W1[row * 3 + k];
        if (k == 3) { if (row < 10) x = B1[row]; else if (row == 10) x = 1.f; }
        break;
      case 1:  // W2 rows 0-15; k=10: B2
        if (k < 10) x = W2[row * 10 + k];
        else if (k == 10) x = B2[row];
        break;
      case 2:  // W2 rows 16-19; k=10: B2[16+]; row4 = bias-1
        if (row < 4 && k < 10) x = W2[(16 + row) * 10 + k];
        if (k == 10) { if (row < 4) x = B2[16 + row]; else if (row == 4) x = 1.f; }
        break;
      case 3:  // W3 k0-15
        if (row < 10 && k < 16) x = W3[row * 20 + k];
        break;
      case 4:  // W3 k16-19; local k4: B3; row10 = bias-1
        if (row < 10 && k < 4) x = W3[row * 20 + 16 + k];
        if (k == 4) { if (row < 10) x = B3[row]; else if (row == 10) x = 1.f; }
        break;
      case 5:  // W4; k=10: B4; row5 = bias-1
        if (row < 5 && k < 10) x = W4[row * 10 + k];
        if (k == 10) { if (row < 5) x = B4[row]; else if (row == 5) x = 1.f; }
        break;
      default:  // W5; k=5: B5
        if (row == 0 && k < 5) x = W5[k];
        if (row == 0 && k == 5) x = B5[0];
        break;
    }
    v[i] = x;
  }
  Wf[p] = uint2{pk_u32(v[0], v[1]), pk_u32(v[2], v[3])};
}

__device__ __forceinline__ floatx4 mfma16(half4 a, half4 b, floatx4 c) {
  return __builtin_amdgcn_mfma_f32_16x16x16f16(a, b, c, 0, 0, 0);
}

// One WAVE per graph; both loops depth-1 software-pipelined (next iteration's
// loads issued before current iteration's compute consumes its values).
// 1024-thread blocks: 16 waves/block, 2 blocks/CU = full 32-wave residency.
__global__ __launch_bounds__(1024, 8) void fused_kernel(
    const float* __restrict__ t, const float2* __restrict__ pos,
    const float* __restrict__ poi_t, const float2* __restrict__ poi_pos,
    const int* __restrict__ start, const uint2* __restrict__ Wf,
    float* __restrict__ out) {
  const int tid = threadIdx.x;
  const int lane = tid & 63;
  const int wid = tid >> 6;
  const int col = lane & 15;
  const int koct = lane >> 4;
  const int g = blockIdx.x * 16 + wid;

  int s = start[g], e = start[g + 1];
  float2 pp = poi_pos[g];
  float pt = poi_t[g];
  int niter = (e - s + 63) >> 6;

  // ---- Centroid (depth-1 pipelined load->reduce) ----
  float cx = 0.f, cy = 0.f;
  {
    int idx0 = s + lane;
    float2 pA = pos[min(idx0, NNODES - 1)];
    for (int it = 0; it < niter; ++it) {
      int nidx = s + (it + 1) * 64 + lane;
      float2 pB;
      if (it + 1 < niter) pB = pos[min(nidx, NNODES - 1)];
      int idx = s + it * 64 + lane;
      if (idx < e) { cx += pA.x; cy += pA.y; }
      pA = pB;
    }
  }
  cx = wave_sum(cx);
  cy = wave_sum(cy);
  cx = __shfl(cx, 63);
  cy = __shfl(cy, 63);
  float dcx = cx - pp.x, dcy = cy - pp.y;
  float invc = rsqrtf(dcx * dcx + dcy * dcy);
  float ucx = dcx * invc, ucy = dcy * invc;

  // Weight A-fragments (biases folded -> C operand is zero).
  half4 wa[7];
#pragma unroll
  for (int k = 0; k < 7; ++k)
    wa[k] = __builtin_bit_cast(half4, Wf[k * 64 + lane]);
  floatx4 cz{0.f, 0.f, 0.f, 0.f};

  // ---- MLP + weighted-unit accumulation (depth-1 pipelined) ----
  float ox = 0.f, oy = 0.f;
  {
    int idx0c = min(s + lane, NNODES - 1);
    float tvA = t[idx0c];
    float2 pvA = pos[idx0c];
    for (int it = 0; it < niter; ++it) {
      // Issue next iteration's loads NOW (hide under the MFMA chain).
      float tvB;
      float2 pvB;
      if (it + 1 < niter) {
        int nidxc = min(s + (it + 1) * 64 + lane, NNODES - 1);
        tvB = t[nidxc];
        pvB = pos[nidxc];
      }

      int idx = s + it * 64 + lane;
      bool valid = idx < e;
      float f0 = tvA - pt;
      float dpx = pvA.x - pp.x, dpy = pvA.y - pp.y;
      float f1 = dpx * dpx + dpy * dpy;
      float invr = rsqrtf(f1);
      float f2 = (dpx * ucx + dpy * ucy) * invr;
      int fx = (int)pk_u32(f0, f1);
      int fy = (int)pk_u32(f2, 1.0f);  // 1.0 feeds the folded-bias column

      half4 b1[4];
#pragma unroll
      for (int g2 = 0; g2 < 4; ++g2) {
        int src = g2 * 16 + col;
        uint2 fr;
        fr.x = (uint)__shfl(fx, src);
        fr.y = (uint)__shfl(fy, src);
        b1[g2] = __builtin_bit_cast(half4, fr);
      }

      floatx4 d[4];
      half4 a[4];
#pragma unroll
      for (int c = 0; c < 4; ++c) d[c] = mfma16(wa[0], b1[c], cz);   // L1
#pragma unroll
      for (int c = 0; c < 4; ++c) a[c] = relu_cvt(d[c]);

      floatx4 d2[4];
      half4 a3a[4], a3b[4];
#pragma unroll
      for (int c = 0; c < 4; ++c) d2[c] = mfma16(wa[1], a[c], cz);   // L2a
#pragma unroll
      for (int c = 0; c < 4; ++c) a3a[c] = relu_cvt(d2[c]);
#pragma unroll
      for (int c = 0; c < 4; ++c) d2[c] = mfma16(wa[2], a[c], cz);   // L2b
#pragma unroll
      for (int c = 0; c < 4; ++c) a3b[c] = relu_cvt(d2[c]);

#pragma unroll
      for (int c = 0; c < 4; ++c) d[c] = mfma16(wa[3], a3a[c], cz);  // L3a
#pragma unroll
      for (int c = 0; c < 4; ++c) d[c] = mfma16(wa[4], a3b[c], d[c]); // L3b
#pragma unroll
      for (int c = 0; c < 4; ++c) a[c] = relu_cvt(d[c]);

#pragma unroll
      for (int c = 0; c < 4; ++c) d[c] = mfma16(wa[5], a[c], cz);    // L4
#pragma unroll
      for (int c = 0; c < 4; ++c) a[c] = relu_cvt(d[c]);

#pragma unroll
      for (int c = 0; c < 4; ++c) d[c] = mfma16(wa[6], a[c], cz);    // L5

      float wg0 = __shfl(d[0][0], col);
      float wg1 = __shfl(d[1][0], col);
      float wg2 = __shfl(d[2][0], col);
      float wg3 = __shfl(d[3][0], col);
      float w = wg0;
      w = (koct == 1) ? wg1 : w;
      w = (koct == 2) ? wg2 : w;
      w = (koct == 3) ? wg3 : w;
      float invn = (f1 > 0.f) ? invr : 0.f;
      if (valid) {
        ox += w * dpx * invn;
        oy += w * dpy * invn;
      }

      tvA = tvB;
      pvA = pvB;
    }
  }

  ox = wave_sum(ox);
  oy = wave_sum(oy);
  if (lane == 63) ((float2*)out)[g] = float2{ox, oy};
}

extern "C" void kernel_launch(void* const* d_in, const int* in_sizes, int n_in,
                              void* d_out, int out_size, void* d_ws,
                              size_t ws_size, hipStream_t stream) {
  const float* t = (const float*)d_in[0];
  const float2* pos = (const float2*)d_in[1];
  const float* poi_t = (const float*)d_in[2];
  const float2* poi_pos = (const float2*)d_in[3];
  const int* batch = (const int*)d_in[4];
  const float* W1 = (const float*)d_in[5];
  const float* B1 = (const float*)d_in[6];
  const float* W2 = (const float*)d_in[7];
  const float* B2 = (const float*)d_in[8];
  const float* W3 = (const float*)d_in[9];
  const float* B3 = (const float*)d_in[10];
  const float* W4 = (const float*)d_in[11];
  const float* B4 = (const float*)d_in[12];
  const float* W5 = (const float*)d_in[13];
  const float* B5 = (const float*)d_in[14];
  float* out = (float*)d_out;

  int* start = (int*)d_ws;                     // [NGRAPH+1]
  uint2* Wf = (uint2*)(start + NGRAPH + 1);    // [448]

  prepack_kernel<<<2, 256, 0, stream>>>(W1, W2, W3, W4, W5, B1, B2, B3, B4,
                                        B5, Wf);
  scan_kernel<<<NNODES / 256, 256, 0, stream>>>(batch, start);
  fused_kernel<<<NGRAPH / 16, 1024, 0, stream>>>(t, pos, poi_t, poi_pos,
                                                 start, Wf, out);
}